// Round 7
// baseline (1007.176 us; speedup 1.0000x reference)
//
#include <hip/hip_runtime.h>

typedef __bf16 bf16;
typedef __bf16 bf16x4 __attribute__((ext_vector_type(4)));
typedef __bf16 bf16x8 __attribute__((ext_vector_type(8)));
typedef float floatx4 __attribute__((ext_vector_type(4)));

typedef __attribute__((address_space(1))) const void gvoid_t;
typedef __attribute__((address_space(3))) void lvoid_t;

#define B_DIM 8
#define S_DIM 4096
#define M_DIM 32768
#define CHUNK 128
#define NCHUNK 32

__device__ __forceinline__ void gload_lds16(const bf16* g, bf16* l) {
    __builtin_amdgcn_global_load_lds((gvoid_t*)g, (lvoid_t*)l, 16, 0, 0);
}

__device__ __forceinline__ float gelu_tanh(float x) {
    float x3 = x * x * x;
    return 0.5f * x * (1.0f + tanhf(0.7978845608028654f * (x + 0.044715f * x3)));
}

__device__ __forceinline__ float sigmoidf(float z) {
    return 1.0f / (1.0f + expf(-z));
}

// ---------------- weight transpose (f32 -> bf16, W^T), LDS-tiled ----------------
__global__ void prep_weights(const float* __restrict__ W0, const float* __restrict__ W1,
                             const float* __restrict__ W2, const float* __restrict__ W3,
                             const float* __restrict__ W4, const float* __restrict__ W5,
                             bf16* __restrict__ T0, bf16* __restrict__ T1,
                             bf16* __restrict__ T2, bf16* __restrict__ T3,
                             bf16* __restrict__ T4, bf16* __restrict__ T5) {
    __shared__ float tile[32][33];
    int mz = blockIdx.z;
    const float* W = mz == 0 ? W0 : mz == 1 ? W1 : mz == 2 ? W2 : mz == 3 ? W3 : mz == 4 ? W4 : W5;
    bf16* T = mz == 0 ? T0 : mz == 1 ? T1 : mz == 2 ? T2 : mz == 3 ? T3 : mz == 4 ? T4 : T5;
    int tn = blockIdx.x * 32;
    int tk = blockIdx.y * 32;
    int tx = threadIdx.x & 31, ty = threadIdx.x >> 5;   // ty 0..7
#pragma unroll
    for (int i = 0; i < 4; ++i)
        tile[ty + i * 8][tx] = W[(size_t)(tk + ty + i * 8) * 1024 + tn + tx];
    __syncthreads();
#pragma unroll
    for (int i = 0; i < 4; ++i)
        T[(size_t)(tn + ty + i * 8) * 1024 + tk + tx] = (bf16)tile[tx][ty + i * 8];
}

__global__ void sp_kernel(const float* __restrict__ a_param, float* __restrict__ spbuf) {
    int d = blockIdx.x * 256 + threadIdx.x;
    spbuf[d] = log1pf(expf(a_param[d]));
}

// ---------------- gelu: x (f32) -> xg (bf16) ----------------
__global__ void gelu_kernel(const float* __restrict__ x, bf16* __restrict__ xg) {
    size_t i = (size_t)blockIdx.x * 256 + threadIdx.x;   // over n/4 elements
    float4 v = ((const float4*)x)[i];
    bf16 o0 = (bf16)gelu_tanh(v.x), o1 = (bf16)gelu_tanh(v.y);
    bf16 o2 = (bf16)gelu_tanh(v.z), o3 = (bf16)gelu_tanh(v.w);
    bf16x4 o = {o0, o1, o2, o3};
    ((bf16x4*)xg)[i] = o;
}

// ---------------- N-merged GEMM: C[32768 x 2048] = A @ [B0 | B1] ----------------
// 128x256 tile, 8 waves. One A fetch serves both weight matrices (B0t,B1t adjacent).
// PAIR 0: n<1024 -> out0 = bf16(z+bias0) (u) ; n>=1024 -> out1 = bf16(z+bias1) (v)
// PAIR 1: n<1024 -> out0 = bf16(-8*sigmoid(z+bias0)*sp[gn])         (la, via Wga)
//         n>=1024 -> out1 = bf16(sigmoid(z+bias1)*vbuf[o])          (gxv, via Wgx)
//         (sqrt(-expm1(2*la)) factor deferred into the reverse scans)
template <int PAIR>
__launch_bounds__(512, 4)
__global__ void gemm_pair(const bf16* __restrict__ A, const bf16* __restrict__ Bt,
                          bf16* __restrict__ out0, bf16* __restrict__ out1,
                          const float* __restrict__ bias0, const float* __restrict__ bias1,
                          const float* __restrict__ sp, const bf16* __restrict__ vbuf) {
    __shared__ __align__(16) bf16 lsA[2][4096];
    __shared__ __align__(16) bf16 lsB[4][4096];
    const int tid = threadIdx.x;
    const int wave = tid >> 6;
    const int lane = tid & 63;
    const int lane15 = lane & 15;
    const int quad = lane >> 4;
    const int wm = wave >> 2;
    const int wn = wave & 3;
    // 2048 WGs = 8 XCDs x (32 m-tiles x 8 n-tiles)
    const int blk = blockIdx.x;
    const int xcd = blk & 7;
    const int j = blk >> 3;                     // 0..255
    const long m0 = (long)(xcd * 32 + (j >> 3)) * 128;
    const long n0 = (long)(j & 7) * 256;        // 0..1792
    const int sr = tid >> 3;
    const int sk8 = (tid & 7) ^ (sr & 7);
    const bf16* gA = A + (size_t)(m0 + sr) * 1024 + sk8 * 8;
    const bf16* gB = Bt + (size_t)(n0 + sr) * 1024 + sk8 * 8;

    floatx4 acc[4][4] = {};

    for (int kt = 0; kt < 16; ++kt) {
        __syncthreads();
        gload_lds16(gA + (size_t)kt * 64, &lsA[0][tid * 8]);
        gload_lds16(gA + (size_t)64 * 1024 + kt * 64, &lsA[1][tid * 8]);
#pragma unroll
        for (int i = 0; i < 4; ++i)
            gload_lds16(gB + (size_t)(i * 64) * 1024 + kt * 64, &lsB[i][tid * 8]);
        __syncthreads();
#pragma unroll
        for (int kk = 0; kk < 2; ++kk) {
            bf16x8 af[4], bfr[4];
#pragma unroll
            for (int mi = 0; mi < 4; ++mi) {
                int rl = mi * 16 + lane15;
                af[mi] = *(const bf16x8*)&lsA[wm][rl * 64 + ((kk * 4 + quad) ^ (rl & 7)) * 8];
            }
#pragma unroll
            for (int ni = 0; ni < 4; ++ni) {
                int rl = ni * 16 + lane15;
                bfr[ni] = *(const bf16x8*)&lsB[wn][rl * 64 + ((kk * 4 + quad) ^ (rl & 7)) * 8];
            }
#pragma unroll
            for (int mi = 0; mi < 4; ++mi)
#pragma unroll
                for (int ni = 0; ni < 4; ++ni)
                    acc[mi][ni] = __builtin_amdgcn_mfma_f32_16x16x32_bf16(af[mi], bfr[ni], acc[mi][ni], 0, 0, 0);
        }
    }

    const bool first = (n0 < 1024);             // uniform per WG (n0 multiple of 256)
    bf16* outp = first ? out0 : out1;
    const float* bp = first ? bias0 : bias1;
    const long nb = first ? n0 : (n0 - 1024);
#pragma unroll
    for (int mi = 0; mi < 4; ++mi) {
#pragma unroll
        for (int ni = 0; ni < 4; ++ni) {
            floatx4 v = acc[mi][ni];
            long gn = nb + wn * 64 + ni * 16 + lane15;
#pragma unroll
            for (int r = 0; r < 4; ++r) {
                long gm = m0 + wm * 64 + mi * 16 + quad * 4 + r;
                size_t o = (size_t)gm * 1024 + gn;
                float z = v[r] + bp[gn];
                if (PAIR == 0) {
                    outp[o] = (bf16)z;
                } else {
                    if (first) {
                        outp[o] = (bf16)(-8.0f * sigmoidf(z) * sp[gn]);
                    } else {
                        outp[o] = (bf16)(sigmoidf(z) * (float)vbuf[o]);
                    }
                }
            }
        }
    }
}

// ---------------- concatenated-K GEMM: out = A0@B0t^T + A1@B1t^T + b0 + b1 + xres ----------------
// K=2048 (pointer switch at kt=16), 128x256 / 8-wave. Single f32 write.
__launch_bounds__(512, 4)
__global__ void gemm_cat(const bf16* __restrict__ A0, const bf16* __restrict__ A1,
                         const bf16* __restrict__ B0t, const bf16* __restrict__ B1t,
                         float* __restrict__ outf,
                         const float* __restrict__ bias0, const float* __restrict__ bias1,
                         const float* __restrict__ xres) {
    __shared__ __align__(16) bf16 lsA[2][4096];
    __shared__ __align__(16) bf16 lsB[4][4096];
    const int tid = threadIdx.x;
    const int wave = tid >> 6;
    const int lane = tid & 63;
    const int lane15 = lane & 15;
    const int quad = lane >> 4;
    const int wm = wave >> 2;
    const int wn = wave & 3;
    const int blk = blockIdx.x;
    const int xcd = blk & 7;
    const int j = blk >> 3;
    const long m0 = (long)(xcd * 32 + (j >> 2)) * 128;
    const long n0 = (long)(j & 3) * 256;
    const int sr = tid >> 3;
    const int sk8 = (tid & 7) ^ (sr & 7);

    floatx4 acc[4][4] = {};

    for (int kt = 0; kt < 32; ++kt) {
        const bf16* Ap = (kt < 16) ? A0 : A1;
        const bf16* Bp = (kt < 16) ? B0t : B1t;
        const int ko = kt & 15;
        const bf16* gA = Ap + (size_t)(m0 + sr) * 1024 + sk8 * 8 + (size_t)ko * 64;
        const bf16* gB = Bp + (size_t)(n0 + sr) * 1024 + sk8 * 8 + (size_t)ko * 64;
        __syncthreads();
        gload_lds16(gA, &lsA[0][tid * 8]);
        gload_lds16(gA + (size_t)64 * 1024, &lsA[1][tid * 8]);
#pragma unroll
        for (int i = 0; i < 4; ++i)
            gload_lds16(gB + (size_t)(i * 64) * 1024, &lsB[i][tid * 8]);
        __syncthreads();
#pragma unroll
        for (int kk = 0; kk < 2; ++kk) {
            bf16x8 af[4], bfr[4];
#pragma unroll
            for (int mi = 0; mi < 4; ++mi) {
                int rl = mi * 16 + lane15;
                af[mi] = *(const bf16x8*)&lsA[wm][rl * 64 + ((kk * 4 + quad) ^ (rl & 7)) * 8];
            }
#pragma unroll
            for (int ni = 0; ni < 4; ++ni) {
                int rl = ni * 16 + lane15;
                bfr[ni] = *(const bf16x8*)&lsB[wn][rl * 64 + ((kk * 4 + quad) ^ (rl & 7)) * 8];
            }
#pragma unroll
            for (int mi = 0; mi < 4; ++mi)
#pragma unroll
                for (int ni = 0; ni < 4; ++ni)
                    acc[mi][ni] = __builtin_amdgcn_mfma_f32_16x16x32_bf16(af[mi], bfr[ni], acc[mi][ni], 0, 0, 0);
        }
    }

#pragma unroll
    for (int mi = 0; mi < 4; ++mi) {
#pragma unroll
        for (int ni = 0; ni < 4; ++ni) {
            floatx4 v = acc[mi][ni];
            long gn = n0 + wn * 64 + ni * 16 + lane15;
#pragma unroll
            for (int r = 0; r < 4; ++r) {
                long gm = m0 + wm * 64 + mi * 16 + quad * 4 + r;
                size_t o = (size_t)gm * 1024 + gn;
                outf[o] = v[r] + bias0[gn] + bias1[gn] + xres[o];
            }
        }
    }
}

// ---------------- forward scan (3-pass chunked): h = a*h + u ----------------
// u bf16; 4 adjacent d-channels per thread (8 B loads). 256 blocks = 32 chunks x 8 b.
__global__ void fscan1(const bf16* __restrict__ u, const float* __restrict__ a_fwd,
                       float* __restrict__ carry) {
    int c = blockIdx.x & 31;
    int b = blockIdx.x >> 5;
    int d = threadIdx.x * 4;
    float4 a = *(const float4*)(a_fwd + d);
    const bf16* up = u + ((size_t)(b * S_DIM + c * CHUNK)) * 1024 + d;
    float h0 = 0.0f, h1 = 0.0f, h2 = 0.0f, h3 = 0.0f;
#pragma unroll 4
    for (int t = 0; t < CHUNK; ++t) {
        bf16x4 w = *(const bf16x4*)(up + (size_t)t * 1024);
        h0 = fmaf(a.x, h0, (float)w[0]);
        h1 = fmaf(a.y, h1, (float)w[1]);
        h2 = fmaf(a.z, h2, (float)w[2]);
        h3 = fmaf(a.w, h3, (float)w[3]);
    }
    float4 o = {h0, h1, h2, h3};
    *(float4*)(carry + ((size_t)c * 8 + b) * 1024 + d) = o;
}
__global__ void fscan2(const float* __restrict__ carry, const float* __restrict__ a_fwd,
                       float* __restrict__ H) {
    int idx = blockIdx.x * 256 + threadIdx.x;   // 8192 chains
    int d = idx & 1023, b = idx >> 10;
    float a = a_fwd[d];
    float aL = a;
#pragma unroll
    for (int i = 0; i < 7; ++i) aL *= aL;       // a^128
    float h = 0.0f;
    for (int c = 0; c < NCHUNK; ++c) {
        size_t o = ((size_t)c * 8 + b) * 1024 + d;
        H[o] = h;
        h = fmaf(aL, h, carry[o]);
    }
}
__global__ void fscan3(const bf16* __restrict__ u, const float* __restrict__ a_fwd,
                       const float* __restrict__ H, bf16* __restrict__ hf) {
    int c = blockIdx.x & 31;
    int b = blockIdx.x >> 5;
    int d = threadIdx.x * 4;
    float4 a = *(const float4*)(a_fwd + d);
    const bf16* up = u + ((size_t)(b * S_DIM + c * CHUNK)) * 1024 + d;
    bf16* op = hf + ((size_t)(b * S_DIM + c * CHUNK)) * 1024 + d;
    float4 h = *(const float4*)(H + ((size_t)c * 8 + b) * 1024 + d);
#pragma unroll 4
    for (int t = 0; t < CHUNK; ++t) {
        bf16x4 w = *(const bf16x4*)(up + (size_t)t * 1024);
        h.x = fmaf(a.x, h.x, (float)w[0]);
        h.y = fmaf(a.y, h.y, (float)w[1]);
        h.z = fmaf(a.z, h.z, (float)w[2]);
        h.w = fmaf(a.w, h.w, (float)w[3]);
        bf16x4 ov = {(bf16)h.x, (bf16)h.y, (bf16)h.z, (bf16)h.w};
        *(bf16x4*)(op + (size_t)t * 1024) = ov;
    }
}

// ---------------- reverse RG-LRU scan (3-pass chunked) ----------------
// gxv = sigmoid(z_gx)*v (bf16); effective input = sqrt(-expm1(2*la))*gxv (deferred).
__global__ void bscan1(const bf16* __restrict__ la, const bf16* __restrict__ gxv,
                       float* __restrict__ BL, float* __restrict__ BP) {
    int c = blockIdx.x & 31;
    int b = blockIdx.x >> 5;
    int d = threadIdx.x * 4;
    const bf16* lap = la + ((size_t)(b * S_DIM + c * CHUNK)) * 1024 + d;
    const bf16* gp = gxv + ((size_t)(b * S_DIM + c * CHUNK)) * 1024 + d;
    float h0 = 0.0f, h1 = 0.0f, h2 = 0.0f, h3 = 0.0f;
    float s0 = 0.0f, s1 = 0.0f, s2 = 0.0f, s3 = 0.0f;
#pragma unroll 4
    for (int t = CHUNK - 1; t >= 0; --t) {
        bf16x4 lw = *(const bf16x4*)(lap + (size_t)t * 1024);
        bf16x4 gw = *(const bf16x4*)(gp + (size_t)t * 1024);
        float l0 = (float)lw[0], l1 = (float)lw[1], l2 = (float)lw[2], l3 = (float)lw[3];
        h0 = fmaf(expf(l0), h0, sqrtf(-expm1f(2.0f * l0)) * (float)gw[0]);
        h1 = fmaf(expf(l1), h1, sqrtf(-expm1f(2.0f * l1)) * (float)gw[1]);
        h2 = fmaf(expf(l2), h2, sqrtf(-expm1f(2.0f * l2)) * (float)gw[2]);
        h3 = fmaf(expf(l3), h3, sqrtf(-expm1f(2.0f * l3)) * (float)gw[3]);
        s0 += l0; s1 += l1; s2 += l2; s3 += l3;
    }
    size_t o = ((size_t)c * 8 + b) * 1024 + d;
    float4 hv = {h0, h1, h2, h3};
    float4 pv = {expf(s0), expf(s1), expf(s2), expf(s3)};
    *(float4*)(BL + o) = hv;
    *(float4*)(BP + o) = pv;
}
__global__ void bscan2(const float* __restrict__ BL, const float* __restrict__ BP,
                       float* __restrict__ R) {
    int idx = blockIdx.x * 256 + threadIdx.x;   // 8192 chains
    int d = idx & 1023, b = idx >> 10;
    float r = 0.0f;
    for (int c = NCHUNK - 1; c >= 0; --c) {
        size_t o = ((size_t)c * 8 + b) * 1024 + d;
        R[o] = r;                                // state entering chunk c from the right
        r = fmaf(BP[o], r, BL[o]);
    }
}
__global__ void bscan3(const bf16* __restrict__ la, const bf16* __restrict__ gxv,
                       const float* __restrict__ R, bf16* __restrict__ hb) {
    int c = blockIdx.x & 31;
    int b = blockIdx.x >> 5;
    int d = threadIdx.x * 4;
    const bf16* lap = la + ((size_t)(b * S_DIM + c * CHUNK)) * 1024 + d;
    const bf16* gp = gxv + ((size_t)(b * S_DIM + c * CHUNK)) * 1024 + d;
    bf16* op = hb + ((size_t)(b * S_DIM + c * CHUNK)) * 1024 + d;
    float4 h = *(const float4*)(R + ((size_t)c * 8 + b) * 1024 + d);
#pragma unroll 4
    for (int t = CHUNK - 1; t >= 0; --t) {
        bf16x4 lw = *(const bf16x4*)(lap + (size_t)t * 1024);
        bf16x4 gw = *(const bf16x4*)(gp + (size_t)t * 1024);
        float l0 = (float)lw[0], l1 = (float)lw[1], l2 = (float)lw[2], l3 = (float)lw[3];
        h.x = fmaf(expf(l0), h.x, sqrtf(-expm1f(2.0f * l0)) * (float)gw[0]);
        h.y = fmaf(expf(l1), h.y, sqrtf(-expm1f(2.0f * l1)) * (float)gw[1]);
        h.z = fmaf(expf(l2), h.z, sqrtf(-expm1f(2.0f * l2)) * (float)gw[2]);
        h.w = fmaf(expf(l3), h.w, sqrtf(-expm1f(2.0f * l3)) * (float)gw[3]);
        bf16x4 ov = {(bf16)h.x, (bf16)h.y, (bf16)h.z, (bf16)h.w};
        *(bf16x4*)(op + (size_t)t * 1024) = ov;
    }
}

extern "C" void kernel_launch(void* const* d_in, const int* in_sizes, int n_in,
                              void* d_out, int out_size, void* d_ws, size_t ws_size,
                              hipStream_t stream) {
    const float* x       = (const float*)d_in[0];
    const float* a_fwd   = (const float*)d_in[1];
    const float* Wf1     = (const float*)d_in[2];
    const float* bf1     = (const float*)d_in[3];
    const float* Wf2     = (const float*)d_in[4];
    const float* bf2     = (const float*)d_in[5];
    const float* Wbx     = (const float*)d_in[6];
    const float* bbx     = (const float*)d_in[7];
    const float* Wgx     = (const float*)d_in[8];
    const float* bgx     = (const float*)d_in[9];
    const float* Wga     = (const float*)d_in[10];
    const float* bga     = (const float*)d_in[11];
    const float* a_param = (const float*)d_in[12];
    const float* Wb2     = (const float*)d_in[13];
    const float* bb2     = (const float*)d_in[14];
    float* out = (float*)d_out;
    (void)in_sizes; (void)n_in; (void)out_size; (void)ws_size;

    // ---- workspace layout (~209 MB total) ----
    char* ws = (char*)d_ws;
    size_t off = 0;
    const size_t WSZ = (size_t)1024 * 1024 * 2;          // 2 MB per transposed weight
    bf16* Wf1t = (bf16*)(ws + off); off += WSZ;          // Wf1t|Wbxt adjacent -> pair 0
    bf16* Wbxt = (bf16*)(ws + off); off += WSZ;
    bf16* Wgat = (bf16*)(ws + off); off += WSZ;          // Wgat|Wgxt adjacent -> pair 1
    bf16* Wgxt = (bf16*)(ws + off); off += WSZ;
    bf16* Wf2t = (bf16*)(ws + off); off += WSZ;
    bf16* Wb2t = (bf16*)(ws + off); off += WSZ;
    float* spbuf = (float*)(ws + off); off += 4096;
    const size_t BSZ = (size_t)M_DIM * 1024 * 2;         // 64 MB bf16 [M][1024]
    bf16* buf0 = (bf16*)(ws + off); off += BSZ;          // xg -> hf
    bf16* buf1 = (bf16*)(ws + off); off += BSZ;          // v  -> hb
    bf16* buf2 = (bf16*)(ws + off); off += BSZ;          // la
    float* Fc = (float*)(ws + off); off += (size_t)NCHUNK * 8 * 1024 * 4;
    float* FH = (float*)(ws + off); off += (size_t)NCHUNK * 8 * 1024 * 4;
    float* BL = (float*)(ws + off); off += (size_t)NCHUNK * 8 * 1024 * 4;
    float* BP = (float*)(ws + off); off += (size_t)NCHUNK * 8 * 1024 * 4;
    float* BR = (float*)(ws + off); off += (size_t)NCHUNK * 8 * 1024 * 4;

    bf16* xg = buf0;
    bf16* hf = buf0;            // xg dead before hf written
    bf16* vb = buf1;
    bf16* hb = buf1;            // v dead before hb written
    bf16* la = buf2;
    bf16* ub = (bf16*)d_out;    // d_out as bf16 u scratch (dead before gxv written)
    bf16* gxv = (bf16*)d_out;   // then as bf16 gxv scratch (dead before gemm_cat)

    // 1. prep: transposed bf16 weights + softplus(a_param)
    prep_weights<<<dim3(32, 32, 6), 256, 0, stream>>>(Wf1, Wbx, Wga, Wgx, Wf2, Wb2,
                                                      Wf1t, Wbxt, Wgat, Wgxt, Wf2t, Wb2t);
    sp_kernel<<<4, 256, 0, stream>>>(a_param, spbuf);
    // 2. gelu
    gelu_kernel<<<32768, 256, 0, stream>>>(x, xg);
    // 3+4. merged: u = bf16(xg@Wf1 + bf1) (into d_out) ; v = bf16(xg@Wbx + bbx)
    gemm_pair<0><<<2048, 512, 0, stream>>>(xg, Wf1t, ub, vb, bf1, bbx, nullptr, nullptr);
    // 5. forward scan -> hf (bf16, overwrites xg)
    fscan1<<<256, 256, 0, stream>>>(ub, a_fwd, Fc);
    fscan2<<<32, 256, 0, stream>>>(Fc, a_fwd, FH);
    fscan3<<<256, 256, 0, stream>>>(ub, a_fwd, FH, hf);
    // 6+7. merged: la = bf16(-8*sigmoid(v@Wga+bga)*sp) ; gxv = bf16(sigmoid(v@Wgx+bgx)*v)
    gemm_pair<1><<<2048, 512, 0, stream>>>(vb, Wgat, la, gxv, bga, bgx, spbuf, vb);
    // 8. reverse scan -> hb (bf16, overwrites v); sqrt(-expm1(2la)) applied in-scan
    bscan1<<<256, 256, 0, stream>>>(la, gxv, BL, BP);
    bscan2<<<32, 256, 0, stream>>>(BL, BP, BR);
    bscan3<<<256, 256, 0, stream>>>(la, gxv, BR, hb);
    // 9+10. fused K=2048: out = hf@Wf2 + hb@Wb2 + bf2 + bb2 + x  (single f32 write)
    gemm_cat<<<1024, 512, 0, stream>>>(hf, hb, Wf2t, Wb2t, out, bf2, bb2, x);
}

// Round 8
// 978.340 us; speedup vs baseline: 1.0295x; 1.0295x over previous
//
#include <hip/hip_runtime.h>

typedef __bf16 bf16;
typedef __bf16 bf16x2 __attribute__((ext_vector_type(2)));
typedef __bf16 bf16x4 __attribute__((ext_vector_type(4)));
typedef __bf16 bf16x8 __attribute__((ext_vector_type(8)));
typedef float floatx4 __attribute__((ext_vector_type(4)));

typedef __attribute__((address_space(1))) const void gvoid_t;
typedef __attribute__((address_space(3))) void lvoid_t;

#define B_DIM 8
#define S_DIM 4096
#define M_DIM 32768
#define CH 64
#define NCH 64

__device__ __forceinline__ void gload_lds16(const bf16* g, bf16* l) {
    __builtin_amdgcn_global_load_lds((gvoid_t*)g, (lvoid_t*)l, 16, 0, 0);
}

__device__ __forceinline__ float gelu_tanh(float x) {
    float x3 = x * x * x;
    return 0.5f * x * (1.0f + tanhf(0.7978845608028654f * (x + 0.044715f * x3)));
}

__device__ __forceinline__ float sigmoidf(float z) {
    return 1.0f / (1.0f + expf(-z));
}

// ---------------- weight transpose (f32 -> bf16, W^T), LDS-tiled ----------------
__global__ void prep_weights(const float* __restrict__ W0, const float* __restrict__ W1,
                             const float* __restrict__ W2, const float* __restrict__ W3,
                             const float* __restrict__ W4, const float* __restrict__ W5,
                             bf16* __restrict__ T0, bf16* __restrict__ T1,
                             bf16* __restrict__ T2, bf16* __restrict__ T3,
                             bf16* __restrict__ T4, bf16* __restrict__ T5) {
    __shared__ float tile[32][33];
    int mz = blockIdx.z;
    const float* W = mz == 0 ? W0 : mz == 1 ? W1 : mz == 2 ? W2 : mz == 3 ? W3 : mz == 4 ? W4 : W5;
    bf16* T = mz == 0 ? T0 : mz == 1 ? T1 : mz == 2 ? T2 : mz == 3 ? T3 : mz == 4 ? T4 : T5;
    int tn = blockIdx.x * 32;
    int tk = blockIdx.y * 32;
    int tx = threadIdx.x & 31, ty = threadIdx.x >> 5;   // ty 0..7
#pragma unroll
    for (int i = 0; i < 4; ++i)
        tile[ty + i * 8][tx] = W[(size_t)(tk + ty + i * 8) * 1024 + tn + tx];
    __syncthreads();
#pragma unroll
    for (int i = 0; i < 4; ++i)
        T[(size_t)(tn + ty + i * 8) * 1024 + tk + tx] = (bf16)tile[tx][ty + i * 8];
}

__global__ void sp_kernel(const float* __restrict__ a_param, float* __restrict__ spbuf) {
    int d = blockIdx.x * 256 + threadIdx.x;
    spbuf[d] = log1pf(expf(a_param[d]));
}

// ---------------- gelu: x (f32) -> xg (bf16) ----------------
__global__ void gelu_kernel(const float* __restrict__ x, bf16* __restrict__ xg) {
    size_t i = (size_t)blockIdx.x * 256 + threadIdx.x;   // over n/4 elements
    float4 v = ((const float4*)x)[i];
    bf16 o0 = (bf16)gelu_tanh(v.x), o1 = (bf16)gelu_tanh(v.y);
    bf16 o2 = (bf16)gelu_tanh(v.z), o3 = (bf16)gelu_tanh(v.w);
    bf16x4 o = {o0, o1, o2, o3};
    ((bf16x4*)xg)[i] = o;
}

// ---------------- N-merged GEMM: C[32768 x 2048] = A @ [B0 | B1] ----------------
// 128x256 tile, 8 waves. One A fetch serves both weight matrices (B0t,B1t adjacent).
// PAIR 0: n<1024 -> out0 = bf16(z+bias0) (u) ; n>=1024 -> out1 = bf16(z+bias1) (v)
// PAIR 1: n<1024 -> out0 = bf16(-8*sigmoid(z+bias0)*sp[gn])         (la, via Wga)
//         n>=1024 -> out1 = bf16(sigmoid(z+bias1)*vbuf[o])          (gxv, via Wgx)
//         (sqrt(-expm1(2*la)) factor deferred into the reverse scans)
template <int PAIR>
__launch_bounds__(512, 4)
__global__ void gemm_pair(const bf16* __restrict__ A, const bf16* __restrict__ Bt,
                          bf16* __restrict__ out0, bf16* __restrict__ out1,
                          const float* __restrict__ bias0, const float* __restrict__ bias1,
                          const float* __restrict__ sp, const bf16* __restrict__ vbuf) {
    __shared__ __align__(16) bf16 lsA[2][4096];
    __shared__ __align__(16) bf16 lsB[4][4096];
    const int tid = threadIdx.x;
    const int wave = tid >> 6;
    const int lane = tid & 63;
    const int lane15 = lane & 15;
    const int quad = lane >> 4;
    const int wm = wave >> 2;
    const int wn = wave & 3;
    // 2048 WGs = 8 XCDs x (32 m-tiles x 8 n-tiles)
    const int blk = blockIdx.x;
    const int xcd = blk & 7;
    const int j = blk >> 3;                     // 0..255
    const long m0 = (long)(xcd * 32 + (j >> 3)) * 128;
    const long n0 = (long)(j & 7) * 256;        // 0..1792
    const int sr = tid >> 3;
    const int sk8 = (tid & 7) ^ (sr & 7);
    const bf16* gA = A + (size_t)(m0 + sr) * 1024 + sk8 * 8;
    const bf16* gB = Bt + (size_t)(n0 + sr) * 1024 + sk8 * 8;

    floatx4 acc[4][4] = {};

    for (int kt = 0; kt < 16; ++kt) {
        __syncthreads();
        gload_lds16(gA + (size_t)kt * 64, &lsA[0][tid * 8]);
        gload_lds16(gA + (size_t)64 * 1024 + kt * 64, &lsA[1][tid * 8]);
#pragma unroll
        for (int i = 0; i < 4; ++i)
            gload_lds16(gB + (size_t)(i * 64) * 1024 + kt * 64, &lsB[i][tid * 8]);
        __syncthreads();
#pragma unroll
        for (int kk = 0; kk < 2; ++kk) {
            bf16x8 af[4], bfr[4];
#pragma unroll
            for (int mi = 0; mi < 4; ++mi) {
                int rl = mi * 16 + lane15;
                af[mi] = *(const bf16x8*)&lsA[wm][rl * 64 + ((kk * 4 + quad) ^ (rl & 7)) * 8];
            }
#pragma unroll
            for (int ni = 0; ni < 4; ++ni) {
                int rl = ni * 16 + lane15;
                bfr[ni] = *(const bf16x8*)&lsB[wn][rl * 64 + ((kk * 4 + quad) ^ (rl & 7)) * 8];
            }
#pragma unroll
            for (int mi = 0; mi < 4; ++mi)
#pragma unroll
                for (int ni = 0; ni < 4; ++ni)
                    acc[mi][ni] = __builtin_amdgcn_mfma_f32_16x16x32_bf16(af[mi], bfr[ni], acc[mi][ni], 0, 0, 0);
        }
    }

    const bool first = (n0 < 1024);             // uniform per WG (n0 multiple of 256)
    bf16* outp = first ? out0 : out1;
    const float* bp = first ? bias0 : bias1;
    const long nb = first ? n0 : (n0 - 1024);
#pragma unroll
    for (int mi = 0; mi < 4; ++mi) {
#pragma unroll
        for (int ni = 0; ni < 4; ++ni) {
            floatx4 v = acc[mi][ni];
            long gn = nb + wn * 64 + ni * 16 + lane15;
#pragma unroll
            for (int r = 0; r < 4; ++r) {
                long gm = m0 + wm * 64 + mi * 16 + quad * 4 + r;
                size_t o = (size_t)gm * 1024 + gn;
                float z = v[r] + bp[gn];
                if (PAIR == 0) {
                    outp[o] = (bf16)z;
                } else {
                    if (first) {
                        outp[o] = (bf16)(-8.0f * sigmoidf(z) * sp[gn]);
                    } else {
                        outp[o] = (bf16)(sigmoidf(z) * (float)vbuf[o]);
                    }
                }
            }
        }
    }
}

// ---------------- concatenated-K GEMM: out = A0@B0t^T + A1@B1t^T + b0 + b1 + xres ----------------
// K=2048 (pointer switch at kt=16), 128x256 / 8-wave. Single f32 write.
__launch_bounds__(512, 4)
__global__ void gemm_cat(const bf16* __restrict__ A0, const bf16* __restrict__ A1,
                         const bf16* __restrict__ B0t, const bf16* __restrict__ B1t,
                         float* __restrict__ outf,
                         const float* __restrict__ bias0, const float* __restrict__ bias1,
                         const float* __restrict__ xres) {
    __shared__ __align__(16) bf16 lsA[2][4096];
    __shared__ __align__(16) bf16 lsB[4][4096];
    const int tid = threadIdx.x;
    const int wave = tid >> 6;
    const int lane = tid & 63;
    const int lane15 = lane & 15;
    const int quad = lane >> 4;
    const int wm = wave >> 2;
    const int wn = wave & 3;
    const int blk = blockIdx.x;
    const int xcd = blk & 7;
    const int j = blk >> 3;
    const long m0 = (long)(xcd * 32 + (j >> 2)) * 128;
    const long n0 = (long)(j & 3) * 256;
    const int sr = tid >> 3;
    const int sk8 = (tid & 7) ^ (sr & 7);

    floatx4 acc[4][4] = {};

    for (int kt = 0; kt < 32; ++kt) {
        const bf16* Ap = (kt < 16) ? A0 : A1;
        const bf16* Bp = (kt < 16) ? B0t : B1t;
        const int ko = kt & 15;
        const bf16* gA = Ap + (size_t)(m0 + sr) * 1024 + sk8 * 8 + (size_t)ko * 64;
        const bf16* gB = Bp + (size_t)(n0 + sr) * 1024 + sk8 * 8 + (size_t)ko * 64;
        __syncthreads();
        gload_lds16(gA, &lsA[0][tid * 8]);
        gload_lds16(gA + (size_t)64 * 1024, &lsA[1][tid * 8]);
#pragma unroll
        for (int i = 0; i < 4; ++i)
            gload_lds16(gB + (size_t)(i * 64) * 1024, &lsB[i][tid * 8]);
        __syncthreads();
#pragma unroll
        for (int kk = 0; kk < 2; ++kk) {
            bf16x8 af[4], bfr[4];
#pragma unroll
            for (int mi = 0; mi < 4; ++mi) {
                int rl = mi * 16 + lane15;
                af[mi] = *(const bf16x8*)&lsA[wm][rl * 64 + ((kk * 4 + quad) ^ (rl & 7)) * 8];
            }
#pragma unroll
            for (int ni = 0; ni < 4; ++ni) {
                int rl = ni * 16 + lane15;
                bfr[ni] = *(const bf16x8*)&lsB[wn][rl * 64 + ((kk * 4 + quad) ^ (rl & 7)) * 8];
            }
#pragma unroll
            for (int mi = 0; mi < 4; ++mi)
#pragma unroll
                for (int ni = 0; ni < 4; ++ni)
                    acc[mi][ni] = __builtin_amdgcn_mfma_f32_16x16x32_bf16(af[mi], bfr[ni], acc[mi][ni], 0, 0, 0);
        }
    }

#pragma unroll
    for (int mi = 0; mi < 4; ++mi) {
#pragma unroll
        for (int ni = 0; ni < 4; ++ni) {
            floatx4 v = acc[mi][ni];
            long gn = n0 + wn * 64 + ni * 16 + lane15;
#pragma unroll
            for (int r = 0; r < 4; ++r) {
                long gm = m0 + wm * 64 + mi * 16 + quad * 4 + r;
                size_t o = (size_t)gm * 1024 + gn;
                outf[o] = v[r] + bias0[gn] + bias1[gn] + xres[o];
            }
        }
    }
}

// ---------------- merged scans: fwd (h=a*h+u) + bwd RG-LRU, 3-pass chunked ----------------
// CHUNK=64, 2 channels/thread: 1024 blocks per role -> 2048-block kernels (4 blk/CU).
// bwd effective input = sqrt(-expm1(2*la)) * gxv (deferred from gemm_pair<1>).
__global__ void scan1(const bf16* __restrict__ u, const float* __restrict__ a_fwd,
                      float* __restrict__ Fc,
                      const bf16* __restrict__ la, const bf16* __restrict__ gxv,
                      float* __restrict__ BL, float* __restrict__ BP) {
    int id = blockIdx.x;
    bool bwd = id >= 1024;
    id &= 1023;
    int dg = id & 1;
    int c = (id >> 1) & 63;
    int b = id >> 7;
    int d = (dg * 256 + threadIdx.x) * 2;
    size_t base = ((size_t)(b * S_DIM + c * CH)) * 1024 + d;
    size_t co = ((size_t)c * 8 + b) * 1024 + d;
    if (!bwd) {
        float a0 = a_fwd[d], a1 = a_fwd[d + 1];
        const bf16* up = u + base;
        float h0 = 0.0f, h1 = 0.0f;
#pragma unroll 8
        for (int t = 0; t < CH; ++t) {
            bf16x2 w = *(const bf16x2*)(up + (size_t)t * 1024);
            h0 = fmaf(a0, h0, (float)w[0]);
            h1 = fmaf(a1, h1, (float)w[1]);
        }
        Fc[co] = h0; Fc[co + 1] = h1;
    } else {
        const bf16* lap = la + base;
        const bf16* gp = gxv + base;
        float h0 = 0.0f, h1 = 0.0f, s0 = 0.0f, s1 = 0.0f;
#pragma unroll 4
        for (int t = CH - 1; t >= 0; --t) {
            bf16x2 lw = *(const bf16x2*)(lap + (size_t)t * 1024);
            bf16x2 gw = *(const bf16x2*)(gp + (size_t)t * 1024);
            float l0 = (float)lw[0], l1 = (float)lw[1];
            h0 = fmaf(expf(l0), h0, sqrtf(-expm1f(2.0f * l0)) * (float)gw[0]);
            h1 = fmaf(expf(l1), h1, sqrtf(-expm1f(2.0f * l1)) * (float)gw[1]);
            s0 += l0; s1 += l1;
        }
        BL[co] = h0; BL[co + 1] = h1;
        BP[co] = expf(s0); BP[co + 1] = expf(s1);
    }
}

__global__ void scan2(const float* __restrict__ Fc, const float* __restrict__ a_fwd,
                      float* __restrict__ FH,
                      const float* __restrict__ BL, const float* __restrict__ BP,
                      float* __restrict__ BR) {
    int bid = blockIdx.x;
    bool bwd = bid >= 32;
    int idx = (bid & 31) * 256 + threadIdx.x;   // 8192 chains
    int d = idx & 1023, b = idx >> 10;
    if (!bwd) {
        float a = a_fwd[d];
        float aL = a;
#pragma unroll
        for (int i = 0; i < 6; ++i) aL *= aL;   // a^64
        float h = 0.0f;
        for (int c = 0; c < NCH; ++c) {
            size_t o = ((size_t)c * 8 + b) * 1024 + d;
            FH[o] = h;
            h = fmaf(aL, h, Fc[o]);
        }
    } else {
        float r = 0.0f;
        for (int c = NCH - 1; c >= 0; --c) {
            size_t o = ((size_t)c * 8 + b) * 1024 + d;
            BR[o] = r;                           // state entering chunk c from the right
            r = fmaf(BP[o], r, BL[o]);
        }
    }
}

__global__ void scan3(const bf16* __restrict__ u, const float* __restrict__ a_fwd,
                      const float* __restrict__ FH, bf16* __restrict__ hf,
                      const bf16* __restrict__ la, const bf16* __restrict__ gxv,
                      const float* __restrict__ BR, bf16* __restrict__ hb) {
    int id = blockIdx.x;
    bool bwd = id >= 1024;
    id &= 1023;
    int dg = id & 1;
    int c = (id >> 1) & 63;
    int b = id >> 7;
    int d = (dg * 256 + threadIdx.x) * 2;
    size_t base = ((size_t)(b * S_DIM + c * CH)) * 1024 + d;
    size_t co = ((size_t)c * 8 + b) * 1024 + d;
    if (!bwd) {
        float a0 = a_fwd[d], a1 = a_fwd[d + 1];
        const bf16* up = u + base;
        bf16* op = hf + base;
        float h0 = FH[co], h1 = FH[co + 1];
#pragma unroll 4
        for (int t = 0; t < CH; ++t) {
            bf16x2 w = *(const bf16x2*)(up + (size_t)t * 1024);
            h0 = fmaf(a0, h0, (float)w[0]);
            h1 = fmaf(a1, h1, (float)w[1]);
            bf16x2 ov = {(bf16)h0, (bf16)h1};
            *(bf16x2*)(op + (size_t)t * 1024) = ov;
        }
    } else {
        const bf16* lap = la + base;
        const bf16* gp = gxv + base;
        bf16* op = hb + base;
        float h0 = BR[co], h1 = BR[co + 1];
#pragma unroll 4
        for (int t = CH - 1; t >= 0; --t) {
            bf16x2 lw = *(const bf16x2*)(lap + (size_t)t * 1024);
            bf16x2 gw = *(const bf16x2*)(gp + (size_t)t * 1024);
            float l0 = (float)lw[0], l1 = (float)lw[1];
            h0 = fmaf(expf(l0), h0, sqrtf(-expm1f(2.0f * l0)) * (float)gw[0]);
            h1 = fmaf(expf(l1), h1, sqrtf(-expm1f(2.0f * l1)) * (float)gw[1]);
            bf16x2 ov = {(bf16)h0, (bf16)h1};
            *(bf16x2*)(op + (size_t)t * 1024) = ov;
        }
    }
}

extern "C" void kernel_launch(void* const* d_in, const int* in_sizes, int n_in,
                              void* d_out, int out_size, void* d_ws, size_t ws_size,
                              hipStream_t stream) {
    const float* x       = (const float*)d_in[0];
    const float* a_fwd   = (const float*)d_in[1];
    const float* Wf1     = (const float*)d_in[2];
    const float* bf1     = (const float*)d_in[3];
    const float* Wf2     = (const float*)d_in[4];
    const float* bf2     = (const float*)d_in[5];
    const float* Wbx     = (const float*)d_in[6];
    const float* bbx     = (const float*)d_in[7];
    const float* Wgx     = (const float*)d_in[8];
    const float* bgx     = (const float*)d_in[9];
    const float* Wga     = (const float*)d_in[10];
    const float* bga     = (const float*)d_in[11];
    const float* a_param = (const float*)d_in[12];
    const float* Wb2     = (const float*)d_in[13];
    const float* bb2     = (const float*)d_in[14];
    float* out = (float*)d_out;
    (void)in_sizes; (void)n_in; (void)out_size; (void)ws_size;

    // ---- workspace layout (~215 MB total) ----
    char* ws = (char*)d_ws;
    size_t off = 0;
    const size_t WSZ = (size_t)1024 * 1024 * 2;          // 2 MB per transposed weight
    bf16* Wf1t = (bf16*)(ws + off); off += WSZ;          // Wf1t|Wbxt adjacent -> pair 0
    bf16* Wbxt = (bf16*)(ws + off); off += WSZ;
    bf16* Wgat = (bf16*)(ws + off); off += WSZ;          // Wgat|Wgxt adjacent -> pair 1
    bf16* Wgxt = (bf16*)(ws + off); off += WSZ;
    bf16* Wf2t = (bf16*)(ws + off); off += WSZ;
    bf16* Wb2t = (bf16*)(ws + off); off += WSZ;
    float* spbuf = (float*)(ws + off); off += 4096;
    const size_t BSZ = (size_t)M_DIM * 1024 * 2;         // 64 MB bf16 [M][1024]
    bf16* buf0 = (bf16*)(ws + off); off += BSZ;          // xg -> hf
    bf16* buf1 = (bf16*)(ws + off); off += BSZ;          // v  -> hb
    bf16* buf2 = (bf16*)(ws + off); off += BSZ;          // la
    const size_t CSZ = (size_t)NCH * 8 * 1024 * 4;       // 2 MB per carry buffer
    float* Fc = (float*)(ws + off); off += CSZ;
    float* FH = (float*)(ws + off); off += CSZ;
    float* BL = (float*)(ws + off); off += CSZ;
    float* BP = (float*)(ws + off); off += CSZ;
    float* BR = (float*)(ws + off); off += CSZ;

    bf16* xg = buf0;
    bf16* hf = buf0;            // xg dead after gemm_pair<0>
    bf16* vb = buf1;
    bf16* hb = buf1;            // v dead after gemm_pair<1>
    bf16* la = buf2;
    bf16* ub = (bf16*)d_out;                      // u   -> d_out lower 64 MB
    bf16* gxv = (bf16*)d_out + (size_t)M_DIM * 1024;  // gxv -> d_out upper 64 MB
    // (both dead before gemm_cat writes out)

    // 1. prep: transposed bf16 weights + softplus(a_param)
    prep_weights<<<dim3(32, 32, 6), 256, 0, stream>>>(Wf1, Wbx, Wga, Wgx, Wf2, Wb2,
                                                      Wf1t, Wbxt, Wgat, Wgxt, Wf2t, Wb2t);
    sp_kernel<<<4, 256, 0, stream>>>(a_param, spbuf);
    // 2. gelu
    gelu_kernel<<<32768, 256, 0, stream>>>(x, xg);
    // 3+4. merged: u = bf16(xg@Wf1 + bf1) ; v = bf16(xg@Wbx + bbx)
    gemm_pair<0><<<2048, 512, 0, stream>>>(xg, Wf1t, ub, vb, bf1, bbx, nullptr, nullptr);
    // 6+7. merged: la = bf16(-8*sigmoid(v@Wga+bga)*sp) ; gxv = bf16(sigmoid(v@Wgx+bgx)*v)
    gemm_pair<1><<<2048, 512, 0, stream>>>(vb, Wgat, la, gxv, bga, bgx, spbuf, vb);
    // 5+8. merged fwd+bwd scans -> hf, hb
    scan1<<<2048, 256, 0, stream>>>(ub, a_fwd, Fc, la, gxv, BL, BP);
    scan2<<<64, 256, 0, stream>>>(Fc, a_fwd, FH, BL, BP, BR);
    scan3<<<2048, 256, 0, stream>>>(ub, a_fwd, FH, hf, la, gxv, BR, hb);
    // 9+10. fused K=2048: out = hf@Wf2 + hb@Wb2 + bf2 + bb2 + x  (single f32 write)
    gemm_cat<<<1024, 512, 0, stream>>>(hf, hb, Wf2t, Wb2t, out, bf2, bb2, x);
}